// Round 13
// baseline (248.524 us; speedup 1.0000x reference)
//
#include <hip/hip_runtime.h>
#include <math.h>

#define HDIM 4096
#define NBLK 128
#define RNK  4
#define TOPK 3

typedef float f4 __attribute__((ext_vector_type(4)));
typedef float f2 __attribute__((ext_vector_type(2)));
typedef _Float16 h2 __attribute__((ext_vector_type(2)));
typedef unsigned int u32;
typedef u32 u4 __attribute__((ext_vector_type(4)));

// fp8 e4m3 (OCP on gfx950) pack/unpack via native ops
__device__ __forceinline__ u32 pk_fp8(f4 v) {
    u32 w = (u32)__builtin_amdgcn_cvt_pk_fp8_f32(v.x, v.y, 0, false);
    w = (u32)__builtin_amdgcn_cvt_pk_fp8_f32(v.z, v.w, (int)w, true);
    return w;
}
__device__ __forceinline__ f2 upk_fp8(u32 w, bool hi) {
    typedef float vf2 __attribute__((ext_vector_type(2)));
    vf2 r = hi ? __builtin_amdgcn_cvt_pk_f32_fp8((int)w, true)
               : __builtin_amdgcn_cvt_pk_f32_fp8((int)w, false);
    f2 o; o.x = r.x; o.y = r.y; return o;
}
__device__ __forceinline__ u32 pk_f16(float a, float b) {
    h2 r; r.x = (_Float16)a; r.y = (_Float16)b;
    return __builtin_bit_cast(u32, r);
}

// ---- preprocessing (VERBATIM r10, passed): A -> fp8 e4m3, same order ----
__global__ __launch_bounds__(256) void convert_A8(
    const float* __restrict__ A, u32* __restrict__ Af8)
{
    int d = blockIdx.x * 256 + threadIdx.x;            // u4 index 0..131071
    const f4* src = reinterpret_cast<const f4*>(A) + 4 * (size_t)d;
    f4 r0 = __builtin_nontemporal_load(src + 0);
    f4 r1 = __builtin_nontemporal_load(src + 1);
    f4 r2 = __builtin_nontemporal_load(src + 2);
    f4 r3 = __builtin_nontemporal_load(src + 3);
    u4 o;
    o.x = pk_fp8(r0); o.y = pk_fp8(r1); o.z = pk_fp8(r2); o.w = pk_fp8(r3);
    reinterpret_cast<u4*>(Af8)[d] = o;
}

// TWO tokens per 256-thread WG, phase-pipelined:
//   {P1(t0); P1(t1)}  barrier  {route+z(t0); route+z(t1)}  barrier  {out x2}
// Selection path is BIT-VERBATIM r12 (passed): fp32 phase-1 FMA order,
// redc + left-assoc coords finalize, same score exprs, verified butterfly
// top-3, same gate sequence. h is stored fp16-packed in LDS (8 KB/token) so
// LDS stays ~16.6 KB; z uses fp16 h (smooth ~2.6e-3, fp8-A dominates) and
// out = (fp16(h) - temb) + delta (~2e-3). Both << 0.108 threshold.
__global__ __launch_bounds__(256) void npl_fused(
    const float* __restrict__ x,
    const int*   __restrict__ task_ids,
    const float* __restrict__ task_emb,
    const float* __restrict__ Wp,
    const float* __restrict__ bp,
    const float* __restrict__ centers,
    const u32*   __restrict__ Af8,
    const float* __restrict__ Bm,
    const float* __restrict__ scale_p,
    float* __restrict__ out,
    int S_per_batch)
{
    __shared__ u32  h_pk[2][HDIM / 2];       // fp16-packed h, 8 KB per token
    __shared__ float redc[2][4][4];
    __shared__ float redz[2][4][12];

    const int tid  = threadIdx.x;
    const int wid  = tid >> 6;
    const int lane = tid & 63;
    const int t0   = blockIdx.x * 2;
    const int t1   = t0 + 1;

    const int b0 = t0 / S_per_batch, b1 = t1 / S_per_batch;
    const int task0 = task_ids[b0], task1 = task_ids[b1];

    const f4* xr0 = reinterpret_cast<const f4*>(x + (size_t)t0 * HDIM);
    const f4* xr1 = reinterpret_cast<const f4*>(x + (size_t)t1 * HDIM);
    const f4* tr0 = reinterpret_cast<const f4*>(task_emb + (size_t)task0 * HDIM);
    const f4* tr1 = reinterpret_cast<const f4*>(task_emb + (size_t)task1 * HDIM);
    f4* or0 = reinterpret_cast<f4*>(out + (size_t)t0 * HDIM);
    f4* or1 = reinterpret_cast<f4*>(out + (size_t)t1 * HDIM);

    // ================= phase 1, token 0 (r12-verbatim arithmetic) ==========
    float c0 = 0.f, c1 = 0.f, c2 = 0.f;
#pragma unroll
    for (int k = 0; k < 4; ++k) {
        int i4 = tid + k * 256;
        f4 xx = __builtin_nontemporal_load(xr0 + i4);
        f4 tt = tr0[i4];
        f4 hh = xx + tt;
        h_pk[0][2 * i4]     = pk_f16(hh.x, hh.y);
        h_pk[0][2 * i4 + 1] = pk_f16(hh.z, hh.w);
        int e = i4 * 4;
        const float* wrow = Wp + (size_t)e * 3;
        c0 += hh.x * wrow[0];  c1 += hh.x * wrow[1];  c2 += hh.x * wrow[2];
        c0 += hh.y * wrow[3];  c1 += hh.y * wrow[4];  c2 += hh.y * wrow[5];
        c0 += hh.z * wrow[6];  c1 += hh.z * wrow[7];  c2 += hh.z * wrow[8];
        c0 += hh.w * wrow[9];  c1 += hh.w * wrow[10]; c2 += hh.w * wrow[11];
    }
#pragma unroll
    for (int off = 32; off; off >>= 1) {
        c0 += __shfl_down(c0, off);
        c1 += __shfl_down(c1, off);
        c2 += __shfl_down(c2, off);
    }
    if (lane == 0) { redc[0][wid][0] = c0; redc[0][wid][1] = c1; redc[0][wid][2] = c2; }

    // ================= phase 1, token 1 ====================================
    c0 = 0.f; c1 = 0.f; c2 = 0.f;
#pragma unroll
    for (int k = 0; k < 4; ++k) {
        int i4 = tid + k * 256;
        f4 xx = __builtin_nontemporal_load(xr1 + i4);
        f4 tt = tr1[i4];
        f4 hh = xx + tt;
        h_pk[1][2 * i4]     = pk_f16(hh.x, hh.y);
        h_pk[1][2 * i4 + 1] = pk_f16(hh.z, hh.w);
        int e = i4 * 4;
        const float* wrow = Wp + (size_t)e * 3;
        c0 += hh.x * wrow[0];  c1 += hh.x * wrow[1];  c2 += hh.x * wrow[2];
        c0 += hh.y * wrow[3];  c1 += hh.y * wrow[4];  c2 += hh.y * wrow[5];
        c0 += hh.z * wrow[6];  c1 += hh.z * wrow[7];  c2 += hh.z * wrow[8];
        c0 += hh.w * wrow[9];  c1 += hh.w * wrow[10]; c2 += hh.w * wrow[11];
    }
#pragma unroll
    for (int off = 32; off; off >>= 1) {
        c0 += __shfl_down(c0, off);
        c1 += __shfl_down(c1, off);
        c2 += __shfl_down(c2, off);
    }
    if (lane == 0) { redc[1][wid][0] = c0; redc[1][wid][1] = c1; redc[1][wid][2] = c2; }

    __syncthreads();   // barrier 1 of 2

    // route + z for a token T: macro-free explicit pair to keep static regs
    int n0a, n1a, n2a; float g0a, g1a, g2a;
    int n0b, n1b, n2b; float g0b, g1b, g2b;
    const float sgl = scale_p[0];

#define ROUTE_AND_Z(T, N0, N1, N2, G0, G1, G2)                                    \
    {                                                                             \
        float cc0 = redc[T][0][0] + redc[T][1][0] + redc[T][2][0] + redc[T][3][0] + bp[0]; \
        float cc1 = redc[T][0][1] + redc[T][1][1] + redc[T][2][1] + redc[T][3][1] + bp[1]; \
        float cc2 = redc[T][0][2] + redc[T][1][2] + redc[T][2][2] + redc[T][3][2] + bp[2]; \
        float dx = cc0 - centers[lane * 3 + 0];                                   \
        float dy = cc1 - centers[lane * 3 + 1];                                   \
        float dz = cc2 - centers[lane * 3 + 2];                                   \
        float v1 = -0.5f * (dx * dx + dy * dy + dz * dz);                         \
        dx = cc0 - centers[(lane + 64) * 3 + 0];                                  \
        dy = cc1 - centers[(lane + 64) * 3 + 1];                                  \
        dz = cc2 - centers[(lane + 64) * 3 + 2];                                  \
        float v2 = -0.5f * (dx * dx + dy * dy + dz * dz);                         \
        float av, bv, cv; int ai, bi, ci;                                         \
        {                                                                         \
            bool f = (v1 > v2) || (v1 == v2);                                     \
            av = f ? v1 : v2;  ai = f ? lane : (lane + 64);                       \
            bv = f ? v2 : v1;  bi = f ? (lane + 64) : lane;                       \
            cv = -3.0e38f;     ci = 0x7fffffff;                                   \
        }                                                                         \
        _Pragma("unroll")                                                         \
        for (int off = 1; off < 64; off <<= 1) {                                  \
            float oav = __shfl_xor(av, off); int oai = __shfl_xor(ai, off);       \
            float obv = __shfl_xor(bv, off); int obi = __shfl_xor(bi, off);       \
            float ocv = __shfl_xor(cv, off); int oci = __shfl_xor(ci, off);       \
            bool u0 = (av > oav) || (av == oav && ai < oai);                      \
            float r0v = u0 ? av : oav;  int r0i = u0 ? ai : oai;                  \
            float lhv = u0 ? bv : av;   int lhi = u0 ? bi : ai;                   \
            float lnv = u0 ? cv : bv;   int lni = u0 ? ci : bi;                   \
            float mhv = u0 ? oav : obv; int mhi = u0 ? oai : obi;                 \
            float mnv = u0 ? obv : ocv; int mni = u0 ? obi : oci;                 \
            bool u1 = (lhv > mhv) || (lhv == mhv && lhi < mhi);                   \
            float r1v = u1 ? lhv : mhv; int r1i = u1 ? lhi : mhi;                 \
            float l2v = u1 ? lnv : lhv; int l2i = u1 ? lni : lhi;                 \
            float m2v = u1 ? mhv : mnv; int m2i = u1 ? mhi : mni;                 \
            bool u2 = (l2v > m2v) || (l2v == m2v && l2i < m2i);                   \
            float r2v = u2 ? l2v : m2v; int r2i = u2 ? l2i : m2i;                 \
            av = r0v; ai = r0i; bv = r1v; bi = r1i; cv = r2v; ci = r2i;           \
        }                                                                         \
        N0 = ai; N1 = bi; N2 = ci;                                                \
        float e1g = expf(bv - av);                                                \
        float e2g = expf(cv - av);                                                \
        float invg = 1.0f / (1.0f + e1g + e2g);                                   \
        G0 = 1.0f * invg * sgl;                                                   \
        G1 = e1g * invg * sgl;                                                    \
        G2 = e2g * invg * sgl;                                                    \
        float zp0[RNK] = {0.f, 0.f, 0.f, 0.f};                                    \
        float zp1[RNK] = {0.f, 0.f, 0.f, 0.f};                                    \
        float zp2[RNK] = {0.f, 0.f, 0.f, 0.f};                                    \
        const u4* A0 = reinterpret_cast<const u4*>(Af8) + (size_t)N0 * 1024;      \
        const u4* A1 = reinterpret_cast<const u4*>(Af8) + (size_t)N1 * 1024;      \
        const u4* A2 = reinterpret_cast<const u4*>(Af8) + (size_t)N2 * 1024;      \
        _Pragma("unroll")                                                         \
        for (int k = 0; k < 4; ++k) {                                             \
            int idx = tid + k * 256;                                              \
            u4 q0 = A0[idx];                                                      \
            u4 q1 = A1[idx];                                                      \
            u4 q2 = A2[idx];                                                      \
            u32 pa = h_pk[T][2 * idx], pb = h_pk[T][2 * idx + 1];                 \
            h2 ha2 = __builtin_bit_cast(h2, pa);                                  \
            h2 hb2 = __builtin_bit_cast(h2, pb);                                  \
            float hx = (float)ha2.x, hy = (float)ha2.y;                           \
            float hz = (float)hb2.x, hw = (float)hb2.y;                           \
            f2 p;                                                                 \
            p = upk_fp8(q0.x, false); zp0[0] += hx * p.x; zp0[1] += hx * p.y;     \
            p = upk_fp8(q0.x, true);  zp0[2] += hx * p.x; zp0[3] += hx * p.y;     \
            p = upk_fp8(q0.y, false); zp0[0] += hy * p.x; zp0[1] += hy * p.y;     \
            p = upk_fp8(q0.y, true);  zp0[2] += hy * p.x; zp0[3] += hy * p.y;     \
            p = upk_fp8(q0.z, false); zp0[0] += hz * p.x; zp0[1] += hz * p.y;     \
            p = upk_fp8(q0.z, true);  zp0[2] += hz * p.x; zp0[3] += hz * p.y;     \
            p = upk_fp8(q0.w, false); zp0[0] += hw * p.x; zp0[1] += hw * p.y;     \
            p = upk_fp8(q0.w, true);  zp0[2] += hw * p.x; zp0[3] += hw * p.y;     \
            p = upk_fp8(q1.x, false); zp1[0] += hx * p.x; zp1[1] += hx * p.y;     \
            p = upk_fp8(q1.x, true);  zp1[2] += hx * p.x; zp1[3] += hx * p.y;     \
            p = upk_fp8(q1.y, false); zp1[0] += hy * p.x; zp1[1] += hy * p.y;     \
            p = upk_fp8(q1.y, true);  zp1[2] += hy * p.x; zp1[3] += hy * p.y;     \
            p = upk_fp8(q1.z, false); zp1[0] += hz * p.x; zp1[1] += hz * p.y;     \
            p = upk_fp8(q1.z, true);  zp1[2] += hz * p.x; zp1[3] += hz * p.y;     \
            p = upk_fp8(q1.w, false); zp1[0] += hw * p.x; zp1[1] += hw * p.y;     \
            p = upk_fp8(q1.w, true);  zp1[2] += hw * p.x; zp1[3] += hw * p.y;     \
            p = upk_fp8(q2.x, false); zp2[0] += hx * p.x; zp2[1] += hx * p.y;     \
            p = upk_fp8(q2.x, true);  zp2[2] += hx * p.x; zp2[3] += hx * p.y;     \
            p = upk_fp8(q2.y, false); zp2[0] += hy * p.x; zp2[1] += hy * p.y;     \
            p = upk_fp8(q2.y, true);  zp2[2] += hy * p.x; zp2[3] += hy * p.y;     \
            p = upk_fp8(q2.z, false); zp2[0] += hz * p.x; zp2[1] += hz * p.y;     \
            p = upk_fp8(q2.z, true);  zp2[2] += hz * p.x; zp2[3] += hz * p.y;     \
            p = upk_fp8(q2.w, false); zp2[0] += hw * p.x; zp2[1] += hw * p.y;     \
            p = upk_fp8(q2.w, true);  zp2[2] += hw * p.x; zp2[3] += hw * p.y;     \
        }                                                                         \
        _Pragma("unroll")                                                         \
        for (int off = 32; off; off >>= 1) {                                      \
            _Pragma("unroll")                                                     \
            for (int r = 0; r < RNK; ++r) {                                       \
                zp0[r] += __shfl_down(zp0[r], off);                               \
                zp1[r] += __shfl_down(zp1[r], off);                               \
                zp2[r] += __shfl_down(zp2[r], off);                               \
            }                                                                     \
        }                                                                         \
        if (lane == 0) {                                                          \
            _Pragma("unroll")                                                     \
            for (int r = 0; r < RNK; ++r) {                                       \
                redz[T][wid][0 * RNK + r] = zp0[r];                               \
                redz[T][wid][1 * RNK + r] = zp1[r];                               \
                redz[T][wid][2 * RNK + r] = zp2[r];                               \
            }                                                                     \
        }                                                                         \
    }

    ROUTE_AND_Z(0, n0a, n1a, n2a, g0a, g1a, g2a)
    ROUTE_AND_Z(1, n0b, n1b, n2b, g0b, g1b, g2b)

    __syncthreads();   // barrier 2 of 2

#define OUT_PHASE(T, TR, OR, N0, N1, N2, G0, G1, G2)                              \
    {                                                                             \
        float zf_[12];                                                            \
        _Pragma("unroll")                                                         \
        for (int t = 0; t < 12; ++t)                                              \
            zf_[t] = redz[T][0][t] + redz[T][1][t] + redz[T][2][t] + redz[T][3][t]; \
        _Pragma("unroll")                                                         \
        for (int k = 0; k < 4; ++k) {                                             \
            int i4 = tid + k * 256;                                               \
            int e = i4 * 4;                                                       \
            int bb = e >> 5;                                                      \
            u32 pa = h_pk[T][2 * i4], pb = h_pk[T][2 * i4 + 1];                   \
            h2 ha2 = __builtin_bit_cast(h2, pa);                                  \
            h2 hb2 = __builtin_bit_cast(h2, pb);                                  \
            f4 tt = TR[i4];                                                       \
            f4 o;                                                                 \
            o.x = (float)ha2.x - tt.x;                                            \
            o.y = (float)ha2.y - tt.y;                                            \
            o.z = (float)hb2.x - tt.z;                                            \
            o.w = (float)hb2.y - tt.w;                                            \
            int kk = (bb == N0) ? 0 : (bb == N1) ? 1 : (bb == N2) ? 2 : -1;       \
            if (kk >= 0) {                                                        \
                int nn = (kk == 0) ? N0 : (kk == 1) ? N1 : N2;                    \
                float za = (kk == 0) ? zf_[0] : (kk == 1) ? zf_[4] : zf_[8];      \
                float zb = (kk == 0) ? zf_[1] : (kk == 1) ? zf_[5] : zf_[9];      \
                float zc = (kk == 0) ? zf_[2] : (kk == 1) ? zf_[6] : zf_[10];     \
                float zd = (kk == 0) ? zf_[3] : (kk == 1) ? zf_[7] : zf_[11];     \
                float gg = (kk == 0) ? G0 : (kk == 1) ? G1 : G2;                  \
                const float* bm = Bm + (size_t)nn * 128;                          \
                int c = e & 31;                                                   \
                float d0 = za * bm[c + 0] + zb * bm[32 + c + 0] + zc * bm[64 + c + 0] + zd * bm[96 + c + 0]; \
                float d1 = za * bm[c + 1] + zb * bm[32 + c + 1] + zc * bm[64 + c + 1] + zd * bm[96 + c + 1]; \
                float d2 = za * bm[c + 2] + zb * bm[32 + c + 2] + zc * bm[64 + c + 2] + zd * bm[96 + c + 2]; \
                float d3 = za * bm[c + 3] + zb * bm[32 + c + 3] + zc * bm[64 + c + 3] + zd * bm[96 + c + 3]; \
                o.x += d0 * gg;                                                   \
                o.y += d1 * gg;                                                   \
                o.z += d2 * gg;                                                   \
                o.w += d3 * gg;                                                   \
            }                                                                     \
            __builtin_nontemporal_store(o, OR + i4);                              \
        }                                                                         \
    }

    OUT_PHASE(0, tr0, or0, n0a, n1a, n2a, g0a, g1a, g2a)
    OUT_PHASE(1, tr1, or1, n0b, n1b, n2b, g0b, g1b, g2b)

#undef ROUTE_AND_Z
#undef OUT_PHASE
}

extern "C" void kernel_launch(void* const* d_in, const int* in_sizes, int n_in,
                              void* d_out, int out_size, void* d_ws, size_t ws_size,
                              hipStream_t stream) {
    const float* x        = (const float*)d_in[0];
    const int*   task_ids = (const int*)  d_in[1];
    const float* task_emb = (const float*)d_in[2];
    const float* Wp       = (const float*)d_in[3];
    const float* bp       = (const float*)d_in[4];
    const float* centers  = (const float*)d_in[5];
    const float* A        = (const float*)d_in[6];
    const float* Bm       = (const float*)d_in[7];
    const float* scale    = (const float*)d_in[8];

    int tokens = in_sizes[0] / HDIM;   // B*S (16384, even)
    int B      = in_sizes[1];
    int S      = tokens / B;

    u32* Af8 = (u32*)d_ws;             // 2 MiB (ws >= 4 MiB proven earlier)

    const int n_u4 = NBLK * HDIM * RNK / 16;     // 131072 u4s
    convert_A8<<<dim3(n_u4 / 256), dim3(256), 0, stream>>>(A, Af8);
    npl_fused<<<dim3(tokens / 2), dim3(256), 0, stream>>>(
        x, task_ids, task_emb, Wp, bp, centers, Af8, Bm, scale,
        (float*)d_out, S);
}

// Round 14
// 214.495 us; speedup vs baseline: 1.1586x; 1.1586x over previous
//
#include <hip/hip_runtime.h>
#include <math.h>

#define HDIM 4096
#define NBLK 128
#define RNK  4
#define TOPK 3

typedef float f4 __attribute__((ext_vector_type(4)));
typedef float f2 __attribute__((ext_vector_type(2)));
typedef unsigned int u32;
typedef u32 u4 __attribute__((ext_vector_type(4)));

// fp8 e4m3 (OCP on gfx950) pack/unpack via native ops
__device__ __forceinline__ u32 pk_fp8(f4 v) {
    u32 w = (u32)__builtin_amdgcn_cvt_pk_fp8_f32(v.x, v.y, 0, false);
    w = (u32)__builtin_amdgcn_cvt_pk_fp8_f32(v.z, v.w, (int)w, true);
    return w;
}
__device__ __forceinline__ f2 upk_fp8(u32 w, bool hi) {
    typedef float vf2 __attribute__((ext_vector_type(2)));
    vf2 r = hi ? __builtin_amdgcn_cvt_pk_f32_fp8((int)w, true)
               : __builtin_amdgcn_cvt_pk_f32_fp8((int)w, false);
    f2 o; o.x = r.x; o.y = r.y; return o;
}
__device__ __forceinline__ f2 sp2(float s) { f2 r; r.x = s; r.y = s; return r; }

// ---- preprocessing (VERBATIM r10, passed): A -> fp8 e4m3, same order ----
__global__ __launch_bounds__(256) void convert_A8(
    const float* __restrict__ A, u32* __restrict__ Af8)
{
    int d = blockIdx.x * 256 + threadIdx.x;            // u4 index 0..131071
    const f4* src = reinterpret_cast<const f4*>(A) + 4 * (size_t)d;
    f4 r0 = __builtin_nontemporal_load(src + 0);
    f4 r1 = __builtin_nontemporal_load(src + 1);
    f4 r2 = __builtin_nontemporal_load(src + 2);
    f4 r3 = __builtin_nontemporal_load(src + 3);
    u4 o;
    o.x = pk_fp8(r0); o.y = pk_fp8(r1); o.z = pk_fp8(r2); o.w = pk_fp8(r3);
    reinterpret_cast<u4*>(Af8)[d] = o;
}

// One workgroup (256 threads) per token. Identical to round 10 (passed,
// 196.7us) except accumulators are packed as f2 pairs so the compiler can
// emit v_pk_fma_f32 (dual FMA/issue):
//  - coords: (c0,c1) packed, c2 scalar  (48 -> ~32 issues/thread)
//  - z: (zp[kk][0],zp[kk][1]) and (zp[kk][2],zp[kk][3]) packed, consuming
//    the f2 that v_cvt_pk_f32_fp8 already returns (96 -> 48 FMA issues)
// Each packed lane keeps its own accumulation chain/order => OUTPUT BITS
// IDENTICAL to round 10. Selection path unchanged.
__global__ __launch_bounds__(256) void npl_fused(
    const float* __restrict__ x,
    const int*   __restrict__ task_ids,
    const float* __restrict__ task_emb,
    const float* __restrict__ Wp,
    const float* __restrict__ bp,
    const float* __restrict__ centers,
    const u32*   __restrict__ Af8,
    const float* __restrict__ Bm,
    const float* __restrict__ scale_p,
    float* __restrict__ out,
    int S_per_batch)
{
    __shared__ float h_lds[HDIM];
    __shared__ float redc[4][4];
    __shared__ float redz[4][12];

    const int tid  = threadIdx.x;
    const int wid  = tid >> 6;
    const int lane = tid & 63;
    const int token = blockIdx.x;
    const int b = token / S_per_batch;
    const int task = task_ids[b];

    const float* xrow = x + (size_t)token * HDIM;
    const float* trow = task_emb + (size_t)task * HDIM;
    float*       orow = out + (size_t)token * HDIM;

    const f4* xr4 = reinterpret_cast<const f4*>(xrow);
    const f4* tr4 = reinterpret_cast<const f4*>(trow);
    f4*       or4 = reinterpret_cast<f4*>(orow);

    // ---- phase 1: stage h to LDS, x in regs, packed coords partials ----
    f4 xv[4];
    f2 c01 = {0.f, 0.f};
    float c2s = 0.f;
#pragma unroll
    for (int k = 0; k < 4; ++k) {
        int i4 = tid + k * 256;
        f4 xx = __builtin_nontemporal_load(xr4 + i4);
        f4 tt = tr4[i4];
        xv[k] = xx;
        f4 hh = xx + tt;
        reinterpret_cast<f4*>(h_lds)[i4] = hh;
        int e = i4 * 4;
        const float* wrow = Wp + (size_t)e * 3;   // 12 consecutive floats
        f2 w;
        w.x = wrow[0];  w.y = wrow[1];  c01 += sp2(hh.x) * w;  c2s += hh.x * wrow[2];
        w.x = wrow[3];  w.y = wrow[4];  c01 += sp2(hh.y) * w;  c2s += hh.y * wrow[5];
        w.x = wrow[6];  w.y = wrow[7];  c01 += sp2(hh.z) * w;  c2s += hh.z * wrow[8];
        w.x = wrow[9];  w.y = wrow[10]; c01 += sp2(hh.w) * w;  c2s += hh.w * wrow[11];
    }
    float c0 = c01.x, c1 = c01.y, c2 = c2s;
#pragma unroll
    for (int off = 32; off; off >>= 1) {
        c0 += __shfl_down(c0, off);
        c1 += __shfl_down(c1, off);
        c2 += __shfl_down(c2, off);
    }
    if (lane == 0) { redc[wid][0] = c0; redc[wid][1] = c1; redc[wid][2] = c2; }
    __syncthreads();   // barrier 1 of 2

    // ---- coords finalize: every thread, exact left-assoc sum (r7) ----
    c0 = redc[0][0] + redc[1][0] + redc[2][0] + redc[3][0] + bp[0];
    c1 = redc[0][1] + redc[1][1] + redc[2][1] + redc[3][1] + bp[1];
    c2 = redc[0][2] + redc[1][2] + redc[2][2] + redc[3][2] + bp[2];

    // ---- scores for blocks `lane` and `lane+64` (r7 expression) ----
    float dx = c0 - centers[lane * 3 + 0];
    float dy = c1 - centers[lane * 3 + 1];
    float dz = c2 - centers[lane * 3 + 2];
    float v1 = -0.5f * (dx * dx + dy * dy + dz * dz);
    dx = c0 - centers[(lane + 64) * 3 + 0];
    dy = c1 - centers[(lane + 64) * 3 + 1];
    dz = c2 - centers[(lane + 64) * 3 + 2];
    float v2 = -0.5f * (dx * dx + dy * dy + dz * dz);

    // ---- top-3 (r7 loop verbatim, redundant on every wave) ----
    float tv0, tv1, tv2; int n0, n1, n2;
#pragma unroll
    for (int kk = 0; kk < TOPK; ++kk) {
        float v = v1; int idx = lane;
        if (v2 > v || (v2 == v && (lane + 64) < idx)) { v = v2; idx = lane + 64; }
#pragma unroll
        for (int off = 32; off; off >>= 1) {
            float ov = __shfl_down(v, off);
            int   oi = __shfl_down(idx, off);
            if (ov > v || (ov == v && oi < idx)) { v = ov; idx = oi; }
        }
        idx = __shfl(idx, 0);
        v   = __shfl(v, 0);
        if (kk == 0)      { tv0 = v; n0 = idx; }
        else if (kk == 1) { tv1 = v; n1 = idx; }
        else              { tv2 = v; n2 = idx; }
        if (idx == lane)      v1 = -3.0e38f;
        if (idx == lane + 64) v2 = -3.0e38f;
    }

    // ---- gates (r7 op sequence) ----
    float m  = tv0;
    float e0 = 1.0f;
    float e1 = expf(tv1 - m);
    float e2 = expf(tv2 - m);
    float inv = 1.0f / (e0 + e1 + e2);
    float s = scale_p[0];
    float g0 = e0 * inv * s;
    float g1 = e1 * inv * s;
    float g2 = e2 * inv * s;

    // ---- z_k = h @ A[n_k]: fp8 decode, packed dual-FMA accumulators ----
    f2 zp01[TOPK], zp23[TOPK];
#pragma unroll
    for (int kk = 0; kk < TOPK; ++kk) {
        zp01[kk].x = 0.f; zp01[kk].y = 0.f;
        zp23[kk].x = 0.f; zp23[kk].y = 0.f;
    }

#pragma unroll
    for (int kk = 0; kk < TOPK; ++kk) {
        int n = (kk == 0) ? n0 : (kk == 1) ? n1 : n2;
        const u4* Ab = reinterpret_cast<const u4*>(Af8) + (size_t)n * 1024;
#pragma unroll
        for (int k = 0; k < 4; ++k) {
            int idx = tid + k * 256;
            u4 q = Ab[idx];                                   // rows 4idx..4idx+3
            f4 hv = reinterpret_cast<const f4*>(h_lds)[idx];
            f2 hx = sp2(hv.x), hy = sp2(hv.y), hz = sp2(hv.z), hw = sp2(hv.w);
            zp01[kk] += hx * upk_fp8(q.x, false);
            zp23[kk] += hx * upk_fp8(q.x, true);
            zp01[kk] += hy * upk_fp8(q.y, false);
            zp23[kk] += hy * upk_fp8(q.y, true);
            zp01[kk] += hz * upk_fp8(q.z, false);
            zp23[kk] += hz * upk_fp8(q.z, true);
            zp01[kk] += hw * upk_fp8(q.w, false);
            zp23[kk] += hw * upk_fp8(q.w, true);
        }
    }
#pragma unroll
    for (int off = 32; off; off >>= 1) {
#pragma unroll
        for (int kk = 0; kk < TOPK; ++kk) {
            zp01[kk].x += __shfl_down(zp01[kk].x, off);
            zp01[kk].y += __shfl_down(zp01[kk].y, off);
            zp23[kk].x += __shfl_down(zp23[kk].x, off);
            zp23[kk].y += __shfl_down(zp23[kk].y, off);
        }
    }
    if (lane == 0) {
#pragma unroll
        for (int kk = 0; kk < TOPK; ++kk) {
            redz[wid][kk * RNK + 0] = zp01[kk].x;
            redz[wid][kk * RNK + 1] = zp01[kk].y;
            redz[wid][kk * RNK + 2] = zp23[kk].x;
            redz[wid][kk * RNK + 3] = zp23[kk].y;
        }
    }
    __syncthreads();   // barrier 2 of 2

    // ---- zf: every thread, left-assoc cross-wave sum (r7) ----
    float zf_[12];
#pragma unroll
    for (int t = 0; t < 12; ++t)
        zf_[t] = redz[0][t] + redz[1][t] + redz[2][t] + redz[3][t];

    // ---- out = x + delta (verbatim r10) ----
#pragma unroll
    for (int k = 0; k < 4; ++k) {
        int i4 = tid + k * 256;
        int e = i4 * 4;          // all 4 elements in the same 32-block
        int bb = e >> 5;
        f4 o = xv[k];
        int kk = (bb == n0) ? 0 : (bb == n1) ? 1 : (bb == n2) ? 2 : -1;
        if (kk >= 0) {
            int nn = (kk == 0) ? n0 : (kk == 1) ? n1 : n2;
            float za = (kk == 0) ? zf_[0] : (kk == 1) ? zf_[4] : zf_[8];
            float zb = (kk == 0) ? zf_[1] : (kk == 1) ? zf_[5] : zf_[9];
            float zc = (kk == 0) ? zf_[2] : (kk == 1) ? zf_[6] : zf_[10];
            float zd = (kk == 0) ? zf_[3] : (kk == 1) ? zf_[7] : zf_[11];
            float gg = (kk == 0) ? g0 : (kk == 1) ? g1 : g2;
            const float* bm = Bm + (size_t)nn * 128;
            int c = e & 31;
            float d0 = za * bm[c + 0] + zb * bm[32 + c + 0] + zc * bm[64 + c + 0] + zd * bm[96 + c + 0];
            float d1 = za * bm[c + 1] + zb * bm[32 + c + 1] + zc * bm[64 + c + 1] + zd * bm[96 + c + 1];
            float d2 = za * bm[c + 2] + zb * bm[32 + c + 2] + zc * bm[64 + c + 2] + zd * bm[96 + c + 2];
            float d3 = za * bm[c + 3] + zb * bm[32 + c + 3] + zc * bm[64 + c + 3] + zd * bm[96 + c + 3];
            o.x += d0 * gg;
            o.y += d1 * gg;
            o.z += d2 * gg;
            o.w += d3 * gg;
        }
        __builtin_nontemporal_store(o, or4 + i4);
    }
}

extern "C" void kernel_launch(void* const* d_in, const int* in_sizes, int n_in,
                              void* d_out, int out_size, void* d_ws, size_t ws_size,
                              hipStream_t stream) {
    const float* x        = (const float*)d_in[0];
    const int*   task_ids = (const int*)  d_in[1];
    const float* task_emb = (const float*)d_in[2];
    const float* Wp       = (const float*)d_in[3];
    const float* bp       = (const float*)d_in[4];
    const float* centers  = (const float*)d_in[5];
    const float* A        = (const float*)d_in[6];
    const float* Bm       = (const float*)d_in[7];
    const float* scale    = (const float*)d_in[8];

    int tokens = in_sizes[0] / HDIM;   // B*S
    int B      = in_sizes[1];
    int S      = tokens / B;

    u32* Af8 = (u32*)d_ws;             // 2 MiB (ws >= 4 MiB proven earlier)

    const int n_u4 = NBLK * HDIM * RNK / 16;     // 131072 u4s
    convert_A8<<<dim3(n_u4 / 256), dim3(256), 0, stream>>>(A, Af8);
    npl_fused<<<dim3(tokens), dim3(256), 0, stream>>>(
        x, task_ids, task_emb, Wp, bp, centers, Af8, Bm, scale,
        (float*)d_out, S);
}

// Round 15
// 201.821 us; speedup vs baseline: 1.2314x; 1.0628x over previous
//
#include <hip/hip_runtime.h>
#include <math.h>

#define HDIM 4096
#define NBLK 128
#define RNK  4
#define TOPK 3

typedef float f4 __attribute__((ext_vector_type(4)));
typedef float f2 __attribute__((ext_vector_type(2)));
typedef unsigned int u32;
typedef u32 u4 __attribute__((ext_vector_type(4)));

// fp8 e4m3 (OCP on gfx950) pack/unpack via native ops
__device__ __forceinline__ u32 pk_fp8(f4 v) {
    u32 w = (u32)__builtin_amdgcn_cvt_pk_fp8_f32(v.x, v.y, 0, false);
    w = (u32)__builtin_amdgcn_cvt_pk_fp8_f32(v.z, v.w, (int)w, true);
    return w;
}
__device__ __forceinline__ f2 upk_fp8(u32 w, bool hi) {
    typedef float vf2 __attribute__((ext_vector_type(2)));
    vf2 r = hi ? __builtin_amdgcn_cvt_pk_f32_fp8((int)w, true)
               : __builtin_amdgcn_cvt_pk_f32_fp8((int)w, false);
    f2 o; o.x = r.x; o.y = r.y; return o;
}

// ---- preprocessing (VERBATIM r10, passed): A -> fp8 e4m3, same order ----
__global__ __launch_bounds__(256) void convert_A8(
    const float* __restrict__ A, u32* __restrict__ Af8)
{
    int d = blockIdx.x * 256 + threadIdx.x;            // u4 index 0..131071
    const f4* src = reinterpret_cast<const f4*>(A) + 4 * (size_t)d;
    f4 r0 = __builtin_nontemporal_load(src + 0);
    f4 r1 = __builtin_nontemporal_load(src + 1);
    f4 r2 = __builtin_nontemporal_load(src + 2);
    f4 r3 = __builtin_nontemporal_load(src + 3);
    u4 o;
    o.x = pk_fp8(r0); o.y = pk_fp8(r1); o.z = pk_fp8(r2); o.w = pk_fp8(r3);
    reinterpret_cast<u4*>(Af8)[d] = o;
}

// One workgroup (256 threads) per token. MINIMUM-VGPR composition of
// previously PASSING pieces (target: <=56 VGPR -> 52% occupancy bin):
//  - phase 1 + coords + scores + 3-pass top-3 + gates: VERBATIM r10 (passed)
//  - z-phase: VERBATIM r10 kk-outer fp8 decode (passed; scalar FMA — r14
//    showed packed is slower)
//  - NO xv[] registers; out = (h_lds - temb) + delta: VERBATIM r12 (passed)
// Selection bits = r10; z bits = r10; out reconstruction validated in r12.
__global__ __launch_bounds__(256) void npl_fused(
    const float* __restrict__ x,
    const int*   __restrict__ task_ids,
    const float* __restrict__ task_emb,
    const float* __restrict__ Wp,
    const float* __restrict__ bp,
    const float* __restrict__ centers,
    const u32*   __restrict__ Af8,
    const float* __restrict__ Bm,
    const float* __restrict__ scale_p,
    float* __restrict__ out,
    int S_per_batch)
{
    __shared__ float h_lds[HDIM];
    __shared__ float redc[4][4];
    __shared__ float redz[4][12];

    const int tid  = threadIdx.x;
    const int wid  = tid >> 6;
    const int lane = tid & 63;
    const int token = blockIdx.x;
    const int b = token / S_per_batch;
    const int task = task_ids[b];

    const float* xrow = x + (size_t)token * HDIM;
    const float* trow = task_emb + (size_t)task * HDIM;
    float*       orow = out + (size_t)token * HDIM;

    const f4* xr4 = reinterpret_cast<const f4*>(xrow);
    const f4* tr4 = reinterpret_cast<const f4*>(trow);
    f4*       or4 = reinterpret_cast<f4*>(orow);

    // ---- phase 1 (verbatim r10, no xv): stage h to LDS, coords partials ----
    float c0 = 0.f, c1 = 0.f, c2 = 0.f;
#pragma unroll
    for (int k = 0; k < 4; ++k) {
        int i4 = tid + k * 256;
        f4 xx = __builtin_nontemporal_load(xr4 + i4);
        f4 tt = tr4[i4];
        f4 hh = xx + tt;
        reinterpret_cast<f4*>(h_lds)[i4] = hh;
        int e = i4 * 4;
        const float* wrow = Wp + (size_t)e * 3;   // 12 consecutive floats
        c0 += hh.x * wrow[0];  c1 += hh.x * wrow[1];  c2 += hh.x * wrow[2];
        c0 += hh.y * wrow[3];  c1 += hh.y * wrow[4];  c2 += hh.y * wrow[5];
        c0 += hh.z * wrow[6];  c1 += hh.z * wrow[7];  c2 += hh.z * wrow[8];
        c0 += hh.w * wrow[9];  c1 += hh.w * wrow[10]; c2 += hh.w * wrow[11];
    }
#pragma unroll
    for (int off = 32; off; off >>= 1) {
        c0 += __shfl_down(c0, off);
        c1 += __shfl_down(c1, off);
        c2 += __shfl_down(c2, off);
    }
    if (lane == 0) { redc[wid][0] = c0; redc[wid][1] = c1; redc[wid][2] = c2; }
    __syncthreads();   // barrier 1 of 2

    // ---- coords finalize: every thread, exact left-assoc sum (r7) ----
    c0 = redc[0][0] + redc[1][0] + redc[2][0] + redc[3][0] + bp[0];
    c1 = redc[0][1] + redc[1][1] + redc[2][1] + redc[3][1] + bp[1];
    c2 = redc[0][2] + redc[1][2] + redc[2][2] + redc[3][2] + bp[2];

    // ---- scores for blocks `lane` and `lane+64` (r7 expression) ----
    float dx = c0 - centers[lane * 3 + 0];
    float dy = c1 - centers[lane * 3 + 1];
    float dz = c2 - centers[lane * 3 + 2];
    float v1 = -0.5f * (dx * dx + dy * dy + dz * dz);
    dx = c0 - centers[(lane + 64) * 3 + 0];
    dy = c1 - centers[(lane + 64) * 3 + 1];
    dz = c2 - centers[(lane + 64) * 3 + 2];
    float v2 = -0.5f * (dx * dx + dy * dy + dz * dz);

    // ---- top-3 (r7 3-pass loop verbatim, redundant on every wave) ----
    float tv0, tv1, tv2; int n0, n1, n2;
#pragma unroll
    for (int kk = 0; kk < TOPK; ++kk) {
        float v = v1; int idx = lane;
        if (v2 > v || (v2 == v && (lane + 64) < idx)) { v = v2; idx = lane + 64; }
#pragma unroll
        for (int off = 32; off; off >>= 1) {
            float ov = __shfl_down(v, off);
            int   oi = __shfl_down(idx, off);
            if (ov > v || (ov == v && oi < idx)) { v = ov; idx = oi; }
        }
        idx = __shfl(idx, 0);
        v   = __shfl(v, 0);
        if (kk == 0)      { tv0 = v; n0 = idx; }
        else if (kk == 1) { tv1 = v; n1 = idx; }
        else              { tv2 = v; n2 = idx; }
        if (idx == lane)      v1 = -3.0e38f;
        if (idx == lane + 64) v2 = -3.0e38f;
    }

    // ---- gates (r7 op sequence) ----
    float m  = tv0;
    float e0 = 1.0f;
    float e1 = expf(tv1 - m);
    float e2 = expf(tv2 - m);
    float inv = 1.0f / (e0 + e1 + e2);
    float s = scale_p[0];
    float g0 = e0 * inv * s;
    float g1 = e1 * inv * s;
    float g2 = e2 * inv * s;

    // ---- z_k = h @ A[n_k] (verbatim r10: fp8 decode, kk-outer, h from LDS) ----
    float zp[TOPK][RNK];
#pragma unroll
    for (int kk = 0; kk < TOPK; ++kk)
#pragma unroll
        for (int r = 0; r < RNK; ++r) zp[kk][r] = 0.f;

#pragma unroll
    for (int kk = 0; kk < TOPK; ++kk) {
        int n = (kk == 0) ? n0 : (kk == 1) ? n1 : n2;
        const u4* Ab = reinterpret_cast<const u4*>(Af8) + (size_t)n * 1024;
#pragma unroll
        for (int k = 0; k < 4; ++k) {
            int idx = tid + k * 256;
            u4 q = Ab[idx];                                   // rows 4idx..4idx+3
            f4 hv = reinterpret_cast<const f4*>(h_lds)[idx];
            f2 p;
            p = upk_fp8(q.x, false); zp[kk][0] += hv.x * p.x; zp[kk][1] += hv.x * p.y;
            p = upk_fp8(q.x, true);  zp[kk][2] += hv.x * p.x; zp[kk][3] += hv.x * p.y;
            p = upk_fp8(q.y, false); zp[kk][0] += hv.y * p.x; zp[kk][1] += hv.y * p.y;
            p = upk_fp8(q.y, true);  zp[kk][2] += hv.y * p.x; zp[kk][3] += hv.y * p.y;
            p = upk_fp8(q.z, false); zp[kk][0] += hv.z * p.x; zp[kk][1] += hv.z * p.y;
            p = upk_fp8(q.z, true);  zp[kk][2] += hv.z * p.x; zp[kk][3] += hv.z * p.y;
            p = upk_fp8(q.w, false); zp[kk][0] += hv.w * p.x; zp[kk][1] += hv.w * p.y;
            p = upk_fp8(q.w, true);  zp[kk][2] += hv.w * p.x; zp[kk][3] += hv.w * p.y;
        }
    }
#pragma unroll
    for (int off = 32; off; off >>= 1) {
#pragma unroll
        for (int kk = 0; kk < TOPK; ++kk)
#pragma unroll
            for (int r = 0; r < RNK; ++r)
                zp[kk][r] += __shfl_down(zp[kk][r], off);
    }
    if (lane == 0) {
#pragma unroll
        for (int kk = 0; kk < TOPK; ++kk)
#pragma unroll
            for (int r = 0; r < RNK; ++r)
                redz[wid][kk * RNK + r] = zp[kk][r];
    }
    __syncthreads();   // barrier 2 of 2

    // ---- zf: every thread, left-assoc cross-wave sum (r7) ----
    float zf_[12];
#pragma unroll
    for (int t = 0; t < 12; ++t)
        zf_[t] = redz[0][t] + redz[1][t] + redz[2][t] + redz[3][t];

    // ---- out = (h_lds - temb) + delta (verbatim r12; nt stores) ----
#pragma unroll
    for (int k = 0; k < 4; ++k) {
        int i4 = tid + k * 256;
        int e = i4 * 4;          // all 4 elements in the same 32-block
        int bb = e >> 5;
        f4 hh = reinterpret_cast<const f4*>(h_lds)[i4];
        f4 tt = tr4[i4];
        f4 o = hh - tt;
        int kk = (bb == n0) ? 0 : (bb == n1) ? 1 : (bb == n2) ? 2 : -1;
        if (kk >= 0) {
            int nn = (kk == 0) ? n0 : (kk == 1) ? n1 : n2;
            float za = (kk == 0) ? zf_[0] : (kk == 1) ? zf_[4] : zf_[8];
            float zb = (kk == 0) ? zf_[1] : (kk == 1) ? zf_[5] : zf_[9];
            float zc = (kk == 0) ? zf_[2] : (kk == 1) ? zf_[6] : zf_[10];
            float zd = (kk == 0) ? zf_[3] : (kk == 1) ? zf_[7] : zf_[11];
            float gg = (kk == 0) ? g0 : (kk == 1) ? g1 : g2;
            const float* bm = Bm + (size_t)nn * 128;
            int c = e & 31;
            float d0 = za * bm[c + 0] + zb * bm[32 + c + 0] + zc * bm[64 + c + 0] + zd * bm[96 + c + 0];
            float d1 = za * bm[c + 1] + zb * bm[32 + c + 1] + zc * bm[64 + c + 1] + zd * bm[96 + c + 1];
            float d2 = za * bm[c + 2] + zb * bm[32 + c + 2] + zc * bm[64 + c + 2] + zd * bm[96 + c + 2];
            float d3 = za * bm[c + 3] + zb * bm[32 + c + 3] + zc * bm[64 + c + 3] + zd * bm[96 + c + 3];
            o.x += d0 * gg;
            o.y += d1 * gg;
            o.z += d2 * gg;
            o.w += d3 * gg;
        }
        __builtin_nontemporal_store(o, or4 + i4);
    }
}

extern "C" void kernel_launch(void* const* d_in, const int* in_sizes, int n_in,
                              void* d_out, int out_size, void* d_ws, size_t ws_size,
                              hipStream_t stream) {
    const float* x        = (const float*)d_in[0];
    const int*   task_ids = (const int*)  d_in[1];
    const float* task_emb = (const float*)d_in[2];
    const float* Wp       = (const float*)d_in[3];
    const float* bp       = (const float*)d_in[4];
    const float* centers  = (const float*)d_in[5];
    const float* A        = (const float*)d_in[6];
    const float* Bm       = (const float*)d_in[7];
    const float* scale    = (const float*)d_in[8];

    int tokens = in_sizes[0] / HDIM;   // B*S
    int B      = in_sizes[1];
    int S      = tokens / B;

    u32* Af8 = (u32*)d_ws;             // 2 MiB (ws >= 4 MiB proven earlier)

    const int n_u4 = NBLK * HDIM * RNK / 16;     // 131072 u4s
    convert_A8<<<dim3(n_u4 / 256), dim3(256), 0, stream>>>(A, Af8);
    npl_fused<<<dim3(tokens), dim3(256), 0, stream>>>(
        x, task_ids, task_emb, Wp, bp, centers, Af8, Bm, scale,
        (float*)d_out, S);
}